// Round 13
// baseline (763.376 us; speedup 1.0000x reference)
//
#include <hip/hip_runtime.h>
#include <hip/hip_bf16.h>

typedef unsigned short ushort_t;
typedef __attribute__((ext_vector_type(4))) float f32x4;
typedef __attribute__((ext_vector_type(8))) short short8;
typedef __attribute__((ext_vector_type(8))) unsigned short ushort8;
typedef __attribute__((ext_vector_type(4))) unsigned short ushort4v;

#define DEV __device__ __forceinline__

static constexpr int S_ = 1024, D_ = 1024, H_ = 16;
static constexpr int R_ = 4096;     // B*S
static constexpr int KE_ = 3072;    // expanded K for split-bf16 (hi|lo|hi)

DEV ushort_t f2bf(float f) {
  union { float f; unsigned u; } a; a.f = f;
  unsigned r = (a.u + 0x7fffu + ((a.u >> 16) & 1u)) >> 16;  // RNE, no NaN inputs
  return (ushort_t)r;
}
DEV float bf2f(ushort_t u) {
  union { unsigned u; float f; } a; a.u = ((unsigned)u) << 16;
  return a.f;
}

DEV void gload16(const void* g, void* l) {
  __builtin_amdgcn_global_load_lds((const __attribute__((address_space(1))) void*)g,
                                   (__attribute__((address_space(3))) void*)l, 16, 0, 0);
}

DEV float mtn4(float x, const float* nwv) {
  float mem = x * 0.5f, sp = 0.0f;
#pragma unroll
  for (int i = 0; i < 4; ++i) {
    float thr = (float)(i + 1);
    if (mem >= thr) { sp += nwv[i] * 0.25f; mem -= thr; }
  }
  return sp;
}

struct GArgs {
  const void* A; const ushort_t* Bm; void* C;
  const ushort_t* Spk;
  const float* bias0; const float* bias1; const float* bias2;
  const float* nw0; const float* nw1; const float* nw2;
  int lda, ldb, ldc, K;
  long long sA1, sA2, sB1, sB2, sC1, sC2, sSpk;
};

// EPI: 0=PROJ(mtn->bf16) 1=COMP(bf16) 2=SCORES(raw f32) 3=PV(bf16 strided) 4=FINAL(mtn->f32)
template<int BM, int BN, int EPI, bool AF32>
__launch_bounds__(256)
__global__ void gemm_bt(GArgs ga) {
  constexpr int BK = 32;
  constexpr int FM = BM / 32, FN = BN / 32;
  constexpr int CHA = BM * BK * 2 / 1024;
  constexpr int CHB = BN * BK * 2 / 1024;
  __shared__ ushort_t As[BM * BK];
  __shared__ ushort_t Bs[BN * BK];

  const int tid = threadIdx.x;
  const int l = tid & 63, w = tid >> 6;
  const int bx = blockIdx.x, by = blockIdx.y, z = blockIdx.z;
  const int zb = z >> 4, zh = z & 15;

  const long long aBase = (long long)zb * ga.sA1 + (long long)zh * ga.sA2 +
                          (long long)by * BM * ga.lda;
  const ushort_t* Bp = ga.Bm + (long long)zb * ga.sB1 + (long long)zh * ga.sB2 +
                       (long long)bx * BN * ga.ldb;

  f32x4 acc[FM][FN];
#pragma unroll
  for (int i = 0; i < FM; ++i)
#pragma unroll
    for (int j = 0; j < FN; ++j) acc[i][j] = (f32x4){0.f, 0.f, 0.f, 0.f};

  for (int kt = 0; kt < ga.K; kt += BK) {
    if constexpr (!AF32) {
      const ushort_t* Ap = (const ushort_t*)ga.A + aBase + kt;
      for (int c = w; c < CHA; c += 4)
        gload16(Ap + (long long)(c * 16 + (l >> 2)) * ga.lda + (l & 3) * 8, &As[c * 512]);
    } else {
      // A is fp32 (attn weights): load 16 floats/thread, convert, ds_write bf16
      const float* Ap = (const float*)ga.A + aBase + kt;
      const int rr = tid >> 1, kh = (tid & 1) * 16;
      const float* sp = Ap + (long long)rr * ga.lda + kh;
      f32x4 f0 = *(const f32x4*)(sp);
      f32x4 f1 = *(const f32x4*)(sp + 4);
      f32x4 f2 = *(const f32x4*)(sp + 8);
      f32x4 f3 = *(const f32x4*)(sp + 12);
      ushort8 u0, u1;
#pragma unroll
      for (int j = 0; j < 4; ++j) {
        u0[j] = f2bf(f0[j]); u0[j + 4] = f2bf(f1[j]);
        u1[j] = f2bf(f2[j]); u1[j + 4] = f2bf(f3[j]);
      }
      *(ushort8*)&As[rr * BK + kh] = u0;
      *(ushort8*)&As[rr * BK + kh + 8] = u1;
    }
    {
      const ushort_t* Bpk = Bp + kt;
      for (int c = w; c < CHB; c += 4)
        gload16(Bpk + (long long)(c * 16 + (l >> 2)) * ga.ldb + (l & 3) * 8, &Bs[c * 512]);
    }
    __syncthreads();
    short8 av[FM], bv[FN];
#pragma unroll
    for (int mi = 0; mi < FM; ++mi)
      av[mi] = *(const short8*)&As[((w >> 1) * (BM / 2) + mi * 16 + (l & 15)) * BK + (l >> 4) * 8];
#pragma unroll
    for (int ni = 0; ni < FN; ++ni)
      bv[ni] = *(const short8*)&Bs[((w & 1) * (BN / 2) + ni * 16 + (l & 15)) * BK + (l >> 4) * 8];
#pragma unroll
    for (int mi = 0; mi < FM; ++mi)
#pragma unroll
      for (int ni = 0; ni < FN; ++ni)
        acc[mi][ni] = __builtin_amdgcn_mfma_f32_16x16x32_bf16(av[mi], bv[ni], acc[mi][ni], 0, 0, 0);
    __syncthreads();
  }

  const int r0 = by * BM + (w >> 1) * (BM / 2);
  const int c0 = bx * BN + (w & 1) * (BN / 2);
  const int rl = (l >> 4) * 4, cl = l & 15;

  if constexpr (EPI == 0 || EPI == 4) {
    const float* bias = (z == 0) ? ga.bias0 : ((z == 1) ? ga.bias1 : ga.bias2);
    const float* nwp = (z == 0) ? ga.nw0 : ((z == 1) ? ga.nw1 : ga.nw2);
    float nwv[4] = {nwp[0], nwp[1], nwp[2], nwp[3]};
#pragma unroll
    for (int mi = 0; mi < FM; ++mi)
#pragma unroll
      for (int ni = 0; ni < FN; ++ni)
#pragma unroll
        for (int i = 0; i < 4; ++i) {
          int row = r0 + mi * 16 + rl + i, col = c0 + ni * 16 + cl;
          float x = acc[mi][ni][i] + bias[col];
          float spv = mtn4(x, nwv);
          if constexpr (EPI == 0)
            ((ushort_t*)ga.C)[(long long)zh * ga.sC2 + (long long)row * ga.ldc + col] = f2bf(spv);
          else
            ((float*)ga.C)[(long long)row * ga.ldc + col] = spv;
        }
  } else if constexpr (EPI == 1) {
    const float* bias = (z == 0) ? ga.bias0 : ((z == 1) ? ga.bias1 : ga.bias2);
    const ushort_t* spk = ga.Spk + (long long)zh * ga.sSpk;
#pragma unroll
    for (int mi = 0; mi < FM; ++mi)
#pragma unroll
      for (int ni = 0; ni < FN; ++ni)
#pragma unroll
        for (int i = 0; i < 4; ++i) {
          int row = r0 + mi * 16 + rl + i, col = c0 + ni * 16 + cl;
          float x = bf2f(spk[(long long)row * 1024 + col]) + (bias[col] - acc[mi][ni][i]);
          ((ushort_t*)ga.C)[(long long)zh * ga.sC2 + (long long)row * ga.ldc + col] = f2bf(x);
        }
  } else if constexpr (EPI == 2) {
#pragma unroll
    for (int mi = 0; mi < FM; ++mi)
#pragma unroll
      for (int ni = 0; ni < FN; ++ni)
#pragma unroll
        for (int i = 0; i < 4; ++i) {
          int row = r0 + mi * 16 + rl + i, col = c0 + ni * 16 + cl;
          ((float*)ga.C)[(long long)zb * ga.sC1 + (long long)zh * ga.sC2 +
                         (long long)row * ga.ldc + col] = acc[mi][ni][i];
        }
  } else {  // PV
#pragma unroll
    for (int mi = 0; mi < FM; ++mi)
#pragma unroll
      for (int ni = 0; ni < FN; ++ni)
#pragma unroll
        for (int i = 0; i < 4; ++i) {
          int row = r0 + mi * 16 + rl + i, col = c0 + ni * 16 + cl;
          ((ushort_t*)ga.C)[(long long)zb * ga.sC1 + (long long)zh * ga.sC2 +
                            (long long)row * ga.ldc + col] = f2bf(acc[mi][ni][i]);
        }
  }
}

__launch_bounds__(256)
__global__ void softmax_rows(float* attn, const float* temperature) {
  const int l = threadIdx.x & 63;
  const long long row = (long long)blockIdx.x * 4 + (threadIdx.x >> 6);
  float* rp = attn + row * 1024;
  const float t = 0.125f / (temperature[0] + 1e-8f);
  f32x4 s[4];
  float m = -3.4e38f;
#pragma unroll
  for (int i = 0; i < 4; ++i) {
    f32x4 x = *(const f32x4*)(rp + 4 * (l + 64 * i));
    s[i] = x * t;
    m = fmaxf(m, fmaxf(fmaxf(s[i][0], s[i][1]), fmaxf(s[i][2], s[i][3])));
  }
#pragma unroll
  for (int off = 32; off; off >>= 1) m = fmaxf(m, __shfl_xor(m, off));
  float sum = 0.f;
#pragma unroll
  for (int i = 0; i < 4; ++i)
#pragma unroll
    for (int j = 0; j < 4; ++j) { s[i][j] = __expf(s[i][j] - m); sum += s[i][j]; }
#pragma unroll
  for (int off = 32; off; off >>= 1) sum += __shfl_xor(sum, off);
  const float inv = 1.0f / sum;
#pragma unroll
  for (int i = 0; i < 4; ++i) {
    f32x4 o = s[i] * inv;
    *(f32x4*)(rp + 4 * (l + 64 * i)) = o;
  }
}

__launch_bounds__(256)
__global__ void transpose_v(const ushort_t* v, ushort_t* vT) {
  __shared__ ushort_t tile[64][65];
  const int tid = threadIdx.x;
  const int tb = blockIdx.x, z = blockIdx.y;
  const int b = z >> 4, h = z & 15;
  const int r = tid >> 2, seg = (tid & 3) * 16;
  const ushort_t* src = v + (long long)b * (S_ * D_) + (long long)(tb * 64 + r) * D_ + h * 64 + seg;
  ushort8 x0 = *(const ushort8*)src;
  ushort8 x1 = *(const ushort8*)(src + 8);
#pragma unroll
  for (int j = 0; j < 8; ++j) { tile[r][seg + j] = x0[j]; tile[r][seg + 8 + j] = x1[j]; }
  __syncthreads();
  ushort8 y0, y1;
#pragma unroll
  for (int j = 0; j < 8; ++j) { y0[j] = tile[seg + j][r]; y1[j] = tile[seg + 8 + j][r]; }
  ushort_t* dst = vT + (long long)z * (64 * 1024) + (long long)r * 1024 + tb * 64 + seg;
  *(ushort8*)dst = y0;
  *(ushort8*)(dst + 8) = y1;
}

__launch_bounds__(256)
__global__ void split_act(const float* q, const float* k, const float* v, ushort_t* Aexp) {
  const long long idx = (long long)blockIdx.x * 256 + threadIdx.x;
  const long long e4 = idx * 4;
  constexpr long long E = (long long)R_ * D_;
  const int z = (int)(e4 / E);
  const long long rem = e4 % E;
  const int r = (int)(rem >> 10), c = (int)(rem & 1023);
  const float* src = (z == 0) ? q : ((z == 1) ? k : v);
  f32x4 x = *(const f32x4*)(src + rem);
  ushort4v hi, lo;
#pragma unroll
  for (int j = 0; j < 4; ++j) { hi[j] = f2bf(x[j]); lo[j] = f2bf(x[j] - bf2f(hi[j])); }
  ushort_t* dst = Aexp + (long long)z * ((long long)R_ * KE_) + (long long)r * KE_ + c;
  *(ushort4v*)dst = hi;
  *(ushort4v*)(dst + 1024) = lo;
  *(ushort4v*)(dst + 2048) = hi;
}

__launch_bounds__(256)
__global__ void split_w3(const float* w0, const float* w1, const float* w2, ushort_t* W3) {
  const long long idx = (long long)blockIdx.x * 256 + threadIdx.x;
  const long long e4 = idx * 4;
  constexpr long long E = (long long)D_ * D_;
  const int z = (int)(e4 / E);
  const long long rem = e4 % E;
  const int r = (int)(rem >> 10), c = (int)(rem & 1023);
  const float* src = (z == 0) ? w0 : ((z == 1) ? w1 : w2);
  f32x4 x = *(const f32x4*)(src + rem);
  ushort4v hi, lo;
#pragma unroll
  for (int j = 0; j < 4; ++j) { hi[j] = f2bf(x[j]); lo[j] = f2bf(x[j] - bf2f(hi[j])); }
  ushort_t* dst = W3 + (long long)z * ((long long)D_ * KE_) + (long long)r * KE_ + c;
  *(ushort4v*)dst = hi;
  *(ushort4v*)(dst + 1024) = hi;
  *(ushort4v*)(dst + 2048) = lo;
}

__launch_bounds__(256)
__global__ void conv_hi4(const float* w0, const float* w1, const float* w2, const float* w3p,
                         ushort_t* Wch, ushort_t* Woh) {
  const long long idx = (long long)blockIdx.x * 256 + threadIdx.x;
  const long long e4 = idx * 4;
  constexpr long long E = (long long)D_ * D_;
  const int z = (int)(e4 / E);
  const long long rem = e4 % E;
  const float* src = (z == 0) ? w0 : ((z == 1) ? w1 : ((z == 2) ? w2 : w3p));
  f32x4 x = *(const f32x4*)(src + rem);
  ushort4v hi;
#pragma unroll
  for (int j = 0; j < 4; ++j) hi[j] = f2bf(x[j]);
  ushort_t* dst = (z < 3) ? (Wch + (long long)z * E + rem) : (Woh + rem);
  *(ushort4v*)dst = hi;
}

extern "C" void kernel_launch(void* const* d_in, const int* in_sizes, int n_in,
                              void* d_out, int out_size, void* d_ws, size_t ws_size,
                              hipStream_t stream) {
  const float* query = (const float*)d_in[0];
  const float* key   = (const float*)d_in[1];
  const float* value = (const float*)d_in[2];
  const float* Wq = (const float*)d_in[3];  const float* bq = (const float*)d_in[4];
  const float* Wk = (const float*)d_in[5];  const float* bk = (const float*)d_in[6];
  const float* Wv = (const float*)d_in[7];  const float* bv = (const float*)d_in[8];
  const float* Wo = (const float*)d_in[9];  const float* bo = (const float*)d_in[10];
  const float* Wqc = (const float*)d_in[11]; const float* bqc = (const float*)d_in[12];
  const float* Wkc = (const float*)d_in[13]; const float* bkc = (const float*)d_in[14];
  const float* Wvc = (const float*)d_in[15]; const float* bvc = (const float*)d_in[16];
  const float* nwq = (const float*)d_in[17];
  const float* nwk = (const float*)d_in[18];
  const float* nwv = (const float*)d_in[19];
  const float* nwo = (const float*)d_in[20];
  const float* temp = (const float*)d_in[21];

  float* out0 = (float*)d_out;
  float* attn = out0 + (long long)R_ * D_;

  char* p = (char*)d_ws;
  auto alloc = [&](long long bytes) { char* r = p; p += (bytes + 255) & ~255LL; return r; };
  ushort_t* Aexp = (ushort_t*)alloc(3LL * R_ * KE_ * 2);
  ushort_t* W3   = (ushort_t*)alloc(3LL * D_ * KE_ * 2);
  ushort_t* Wch  = (ushort_t*)alloc(3LL * D_ * D_ * 2);
  ushort_t* Woh  = (ushort_t*)alloc((long long)D_ * D_ * 2);
  ushort_t* Spk  = (ushort_t*)alloc(3LL * R_ * D_ * 2);
  ushort_t* Qkv  = (ushort_t*)alloc(3LL * R_ * D_ * 2);
  ushort_t* vT   = (ushort_t*)alloc(64LL * 64 * 1024 * 2);
  ushort_t* Aout = (ushort_t*)alloc((long long)R_ * D_ * 2);

  split_act<<<dim3(12288), dim3(256), 0, stream>>>(query, key, value, Aexp);
  split_w3<<<dim3(3072), dim3(256), 0, stream>>>(Wq, Wk, Wv, W3);
  conv_hi4<<<dim3(4096), dim3(256), 0, stream>>>(Wqc, Wkc, Wvc, Wo, Wch, Woh);

  {  // PROJ: spikes = mtn(X @ W^T + b), split-bf16 K=3072, batched over q/k/v
    GArgs ga{};
    ga.A = Aexp; ga.Bm = W3; ga.C = Spk;
    ga.bias0 = bq; ga.bias1 = bk; ga.bias2 = bv;
    ga.nw0 = nwq; ga.nw1 = nwk; ga.nw2 = nwv;
    ga.lda = KE_; ga.ldb = KE_; ga.ldc = D_; ga.K = KE_;
    ga.sA1 = 0; ga.sA2 = (long long)R_ * KE_;
    ga.sB1 = 0; ga.sB2 = (long long)D_ * KE_;
    ga.sC1 = 0; ga.sC2 = (long long)R_ * D_;
    gemm_bt<128, 128, 0, false><<<dim3(8, 32, 3), dim3(256), 0, stream>>>(ga);
  }
  {  // COMP: qkv = spikes - spikes @ Wc^T + bc
    GArgs ga{};
    ga.A = Spk; ga.Bm = Wch; ga.C = Qkv; ga.Spk = Spk;
    ga.bias0 = bqc; ga.bias1 = bkc; ga.bias2 = bvc;
    ga.lda = D_; ga.ldb = D_; ga.ldc = D_; ga.K = D_;
    ga.sA1 = 0; ga.sA2 = (long long)R_ * D_;
    ga.sB1 = 0; ga.sB2 = (long long)D_ * D_;
    ga.sC1 = 0; ga.sC2 = (long long)R_ * D_;
    ga.sSpk = (long long)R_ * D_;
    gemm_bt<128, 128, 1, false><<<dim3(8, 32, 3), dim3(256), 0, stream>>>(ga);
  }
  {  // SCORES: raw q·k^T per (b,h) -> d_out attn region (fp32, unscaled)
    GArgs ga{};
    ga.A = Qkv; ga.Bm = Qkv + (long long)R_ * D_; ga.C = attn;
    ga.lda = D_; ga.ldb = D_; ga.ldc = S_; ga.K = 64;
    ga.sA1 = (long long)S_ * D_; ga.sA2 = 64;
    ga.sB1 = (long long)S_ * D_; ga.sB2 = 64;
    ga.sC1 = 16LL * S_ * S_; ga.sC2 = (long long)S_ * S_;
    gemm_bt<128, 128, 2, false><<<dim3(8, 8, 64), dim3(256), 0, stream>>>(ga);
  }
  softmax_rows<<<dim3(16384), dim3(256), 0, stream>>>(attn, temp);
  transpose_v<<<dim3(16, 64), dim3(256), 0, stream>>>(Qkv + 2LL * R_ * D_, vT);
  {  // PV: attn(fp32, converted in staging) @ vT^T -> attn_out bf16 [B,S,D]
    GArgs ga{};
    ga.A = attn; ga.Bm = vT; ga.C = Aout;
    ga.lda = S_; ga.ldb = S_; ga.ldc = D_; ga.K = S_;
    ga.sA1 = 16LL * S_ * S_; ga.sA2 = (long long)S_ * S_;
    ga.sB1 = 16LL * 64 * S_; ga.sB2 = 64LL * S_;
    ga.sC1 = (long long)S_ * D_; ga.sC2 = 64;
    gemm_bt<128, 64, 3, true><<<dim3(1, 8, 64), dim3(256), 0, stream>>>(ga);
  }
  {  // FINAL: out0 = mtn(attn_out @ Wo^T + bo)
    GArgs ga{};
    ga.A = Aout; ga.Bm = Woh; ga.C = out0;
    ga.bias0 = bo; ga.bias1 = bo; ga.bias2 = bo;
    ga.nw0 = nwo; ga.nw1 = nwo; ga.nw2 = nwo;
    ga.lda = D_; ga.ldb = D_; ga.ldc = D_; ga.K = D_;
    ga.sC1 = 0; ga.sC2 = 0;
    gemm_bt<128, 128, 4, false><<<dim3(8, 32, 1), dim3(256), 0, stream>>>(ga);
  }
}